// Round 2
// baseline (2620.642 us; speedup 1.0000x reference)
//
#include <hip/hip_runtime.h>
#include <math.h>

#define SQ 192      // S
#define BB 192      // B
#define DM 512
#define NH 8
#define DH 64
#define NEPS 1e-5f
#define ASCALE 0.125f   // 1/sqrt(64)

// ---------------------------------------------------------------------------
// Fused double LayerNorm: h = LN2(LN1(inp)). One block (128 thr) per row.
// Reads s-major row (s*B+b), writes b-major row (b*S+s)  -> h' in d_out.
// ---------------------------------------------------------------------------
__global__ __launch_bounds__(128) void ln2_kernel(
    const float* __restrict__ inp, const float* __restrict__ g1, const float* __restrict__ b1,
    const float* __restrict__ g2, const float* __restrict__ b2, float* __restrict__ h) {
  const int R = blockIdx.x;              // input row s*B+b
  const int s = R / BB;
  const int b = R % BB;
  const int t = threadIdx.x;
  const float4 v = reinterpret_cast<const float4*>(inp + (size_t)R * DM)[t];
  float sum  = v.x + v.y + v.z + v.w;
  float sum2 = v.x*v.x + v.y*v.y + v.z*v.z + v.w*v.w;
  #pragma unroll
  for (int o = 32; o >= 1; o >>= 1) { sum += __shfl_xor(sum, o); sum2 += __shfl_xor(sum2, o); }
  __shared__ float red[2][2];
  const int wv = t >> 6;
  if ((t & 63) == 0) { red[0][wv] = sum; red[1][wv] = sum2; }
  __syncthreads();
  sum = red[0][0] + red[0][1]; sum2 = red[1][0] + red[1][1];
  float mu = sum * (1.0f / DM);
  float var = sum2 * (1.0f / DM) - mu * mu;
  float rstd = rsqrtf(var + NEPS);
  const float4 G1 = reinterpret_cast<const float4*>(g1)[t];
  const float4 B1 = reinterpret_cast<const float4*>(b1)[t];
  float4 x;
  x.x = (v.x - mu) * rstd * G1.x + B1.x;
  x.y = (v.y - mu) * rstd * G1.y + B1.y;
  x.z = (v.z - mu) * rstd * G1.z + B1.z;
  x.w = (v.w - mu) * rstd * G1.w + B1.w;
  // second LN
  sum  = x.x + x.y + x.z + x.w;
  sum2 = x.x*x.x + x.y*x.y + x.z*x.z + x.w*x.w;
  #pragma unroll
  for (int o = 32; o >= 1; o >>= 1) { sum += __shfl_xor(sum, o); sum2 += __shfl_xor(sum2, o); }
  __syncthreads();   // protect red reuse
  if ((t & 63) == 0) { red[0][wv] = sum; red[1][wv] = sum2; }
  __syncthreads();
  sum = red[0][0] + red[0][1]; sum2 = red[1][0] + red[1][1];
  mu = sum * (1.0f / DM);
  var = sum2 * (1.0f / DM) - mu * mu;
  rstd = rsqrtf(var + NEPS);
  const float4 G2 = reinterpret_cast<const float4*>(g2)[t];
  const float4 B2 = reinterpret_cast<const float4*>(b2)[t];
  float4 o4;
  o4.x = (x.x - mu) * rstd * G2.x + B2.x;
  o4.y = (x.y - mu) * rstd * G2.y + B2.y;
  o4.z = (x.z - mu) * rstd * G2.z + B2.z;
  o4.w = (x.w - mu) * rstd * G2.w + B2.w;
  reinterpret_cast<float4*>(h + ((size_t)b * SQ + s) * DM)[t] = o4;
}

// ---------------------------------------------------------------------------
// pos_emb[b][d] = sin/cos(pos_seq[b] * inv_freq), pos_seq[b] = inputs[0][b][0]
// ---------------------------------------------------------------------------
__global__ void posemb_kernel(const float* __restrict__ inp, float* __restrict__ pe) {
  const int idx = blockIdx.x * 256 + threadIdx.x;
  if (idx >= BB * DM) return;
  const int b = idx >> 9;
  const int d = idx & 511;
  const float ps = inp[(size_t)b * DM];         // inputs[0][b][0]
  const int i = (d < 256) ? d : (d - 256);
  const float invf = expf(-9.210340371976184f * (float)i * (1.0f / 256.0f));
  const float a = ps * invf;
  pe[idx] = (d < 256) ? sinf(a) : cosf(a);
}

// ---------------------------------------------------------------------------
// r_head_k[j][e] = sum_d pos_emb[j][d] * W_r[e][d]
// ---------------------------------------------------------------------------
__global__ __launch_bounds__(256) void rhk_kernel(
    const float* __restrict__ pe, const float* __restrict__ Wr, float* __restrict__ rhk) {
  __shared__ __align__(16) float pr[DM];
  const int j = blockIdx.x;
  const int e = blockIdx.y * 256 + threadIdx.x;
  for (int d = threadIdx.x; d < DM; d += 256) pr[d] = pe[(size_t)j * DM + d];
  __syncthreads();
  const float4* w4 = reinterpret_cast<const float4*>(Wr + (size_t)e * DM);
  const float4* p4 = reinterpret_cast<const float4*>(pr);
  float acc = 0.f;
  #pragma unroll 8
  for (int d4 = 0; d4 < DM / 4; ++d4) {
    const float4 a = p4[d4];
    const float4 w = w4[d4];
    acc += a.x*w.x + a.y*w.y + a.z*w.z + a.w*w.w;
  }
  rhk[(size_t)j * DM + e] = acc;
}

// ---------------------------------------------------------------------------
// fp32 NT GEMM: C[m][n] = sum_k A[m][k]*Bm[n][k]. 128x128 tile, BK=8, 256 thr,
// 8x8 micro-tile split 4+4 at offset 64.
// permute: 0 -> C row r written at r; 1 -> written at (r%SQ)*BB + r/SQ.
// Grid-y rows must be multiple of 128, K % 8 == 0.
// ---------------------------------------------------------------------------
__global__ __launch_bounds__(256) void gemm_nt(
    const float* __restrict__ A, const float* __restrict__ Bm, float* __restrict__ C,
    int N, int K, int permute) {
  __shared__ __align__(16) float As[8][132];
  __shared__ __align__(16) float Bs[8][132];
  const int bn = blockIdx.x * 128;
  const int bm = blockIdx.y * 128;
  const int tid = threadIdx.x;
  const int lr = tid >> 1;
  const int lk = (tid & 1) << 2;
  const int tx = tid & 15;
  const int ty = tid >> 4;
  const float* Aptr = A + (size_t)(bm + lr) * K + lk;
  const float* Bptr = Bm + (size_t)(bn + lr) * K + lk;
  float acc[8][8];
  #pragma unroll
  for (int r = 0; r < 8; ++r)
    #pragma unroll
    for (int c = 0; c < 8; ++c) acc[r][c] = 0.f;

  for (int k0 = 0; k0 < K; k0 += 8) {
    const float4 av = *reinterpret_cast<const float4*>(Aptr + k0);
    const float4 bv = *reinterpret_cast<const float4*>(Bptr + k0);
    __syncthreads();
    As[lk+0][lr] = av.x; As[lk+1][lr] = av.y; As[lk+2][lr] = av.z; As[lk+3][lr] = av.w;
    Bs[lk+0][lr] = bv.x; Bs[lk+1][lr] = bv.y; Bs[lk+2][lr] = bv.z; Bs[lk+3][lr] = bv.w;
    __syncthreads();
    #pragma unroll
    for (int kk = 0; kk < 8; ++kk) {
      float a[8], b[8];
      #pragma unroll
      for (int r = 0; r < 4; ++r) { a[r] = As[kk][ty*4 + r]; a[r+4] = As[kk][64 + ty*4 + r]; }
      #pragma unroll
      for (int c = 0; c < 4; ++c) { b[c] = Bs[kk][tx*4 + c]; b[c+4] = Bs[kk][64 + tx*4 + c]; }
      #pragma unroll
      for (int r = 0; r < 8; ++r)
        #pragma unroll
        for (int c = 0; c < 8; ++c) acc[r][c] += a[r] * b[c];
    }
  }
  #pragma unroll
  for (int rh = 0; rh < 2; ++rh) {
    #pragma unroll
    for (int rr = 0; rr < 4; ++rr) {
      const int r = rh * 4 + rr;
      const int row = bm + rh * 64 + ty * 4 + rr;
      const int orow = permute ? ((row % SQ) * BB + (row / SQ)) : row;
      float* cp = C + (size_t)orow * N + bn;
      float4 o0 = make_float4(acc[r][0], acc[r][1], acc[r][2], acc[r][3]);
      float4 o1 = make_float4(acc[r][4], acc[r][5], acc[r][6], acc[r][7]);
      *reinterpret_cast<float4*>(cp + tx * 4) = o0;
      *reinterpret_cast<float4*>(cp + 64 + tx * 4) = o1;
    }
  }
}

// ---------------------------------------------------------------------------
// Fused attention per (b,n), b-major qkv chunk.
// scores = (q+rwb)·K^T + rel_shift((q+rrb)·R^T), online softmax, PV.
// rel_shift map: t=(j+191-i) mod 193; t==192 -> 0; row = (j<=i ? i : i+1).
// qkv_c rows are (bl*SQ + s), bl = local batch in chunk; av is full b-major.
// ---------------------------------------------------------------------------
__global__ __launch_bounds__(192) void attn_kernel(
    const float* __restrict__ qkv_c, const float* __restrict__ rhk,
    const float* __restrict__ rwb, const float* __restrict__ rrb,
    float* __restrict__ av, int b0) {
  __shared__ __align__(16) float ks[SQ * DH];        // broadcast reads only
  __shared__ __align__(16) float rs[SQ * (DH + 1)];  // lane-varying rows -> pad
  __shared__ __align__(16) float vs[SQ * DH];        // broadcast reads only
  __shared__ float kbs[SQ];
  __shared__ float rbs[SQ];
  const int bid = blockIdx.x;
  const int n = bid & 7;
  const int bl = bid >> 3;          // local batch index in chunk
  const int b = b0 + bl;            // global batch
  const int tid = threadIdx.x;

  // stage K, V, R tiles
  for (int it = tid; it < SQ * (DH / 4); it += 192) {
    const int j = it >> 4;
    const int c = (it & 15) << 2;
    const float* base = qkv_c + ((size_t)bl * SQ + j) * (3 * DM) + n * DH + c;
    const float4 kv = *reinterpret_cast<const float4*>(base + DM);
    const float4 vv = *reinterpret_cast<const float4*>(base + 2 * DM);
    const float4 rv = *reinterpret_cast<const float4*>(rhk + (size_t)j * DM + n * DH + c);
    *reinterpret_cast<float4*>(&ks[j * DH + c]) = kv;
    *reinterpret_cast<float4*>(&vs[j * DH + c]) = vv;
    rs[j * (DH + 1) + c + 0] = rv.x;
    rs[j * (DH + 1) + c + 1] = rv.y;
    rs[j * (DH + 1) + c + 2] = rv.z;
    rs[j * (DH + 1) + c + 3] = rv.w;
  }
  __syncthreads();
  // bias tables: kb[j] = rwb·k[j], rb[t] = rrb·r[t]
  if (tid < SQ) {
    float ak = 0.f, ar = 0.f;
    #pragma unroll
    for (int d = 0; d < DH; ++d) {
      ak += rwb[n * DH + d] * ks[tid * DH + d];
      ar += rrb[n * DH + d] * rs[tid * (DH + 1) + d];
    }
    kbs[tid] = ak; rbs[tid] = ar;
  }
  // q rows i and i+1 into registers
  const int i = tid;
  float qi[DH], qp[DH];
  {
    const float* q0 = qkv_c + ((size_t)bl * SQ + i) * (3 * DM) + n * DH;
    const int i2 = (i < SQ - 1) ? i + 1 : i;
    const float* q1 = qkv_c + ((size_t)bl * SQ + i2) * (3 * DM) + n * DH;
    #pragma unroll
    for (int d4 = 0; d4 < DH / 4; ++d4) {
      const float4 t0 = reinterpret_cast<const float4*>(q0)[d4];
      qi[d4*4+0] = t0.x; qi[d4*4+1] = t0.y; qi[d4*4+2] = t0.z; qi[d4*4+3] = t0.w;
      const float4 t1 = reinterpret_cast<const float4*>(q1)[d4];
      qp[d4*4+0] = t1.x; qp[d4*4+1] = t1.y; qp[d4*4+2] = t1.z; qp[d4*4+3] = t1.w;
    }
  }
  __syncthreads();

  float m = -1e30f, l = 0.f;
  float acc[DH];
  #pragma unroll
  for (int d = 0; d < DH; ++d) acc[d] = 0.f;

  for (int j = 0; j < SQ; ++j) {
    int t = j + (SQ - 1) - i;
    if (t >= SQ + 1) t -= (SQ + 1);          // mod 193
    const bool valid = (t != SQ);            // t==192 -> zero BD
    const int tt = valid ? t : 0;
    float ac = 0.f, bd1 = 0.f, bd2 = 0.f;
    #pragma unroll
    for (int d4 = 0; d4 < DH / 4; ++d4) {
      const float4 kv = *reinterpret_cast<const float4*>(&ks[j * DH + d4 * 4]);
      ac += qi[d4*4+0]*kv.x + qi[d4*4+1]*kv.y + qi[d4*4+2]*kv.z + qi[d4*4+3]*kv.w;
    }
    #pragma unroll
    for (int d = 0; d < DH; ++d) {
      const float rv = rs[tt * (DH + 1) + d];
      bd1 += qi[d] * rv;
      bd2 += qp[d] * rv;
    }
    const float bd = (j <= i) ? bd1 : bd2;
    float sv = ac + kbs[j] + (valid ? (bd + rbs[tt]) : 0.f);
    sv *= ASCALE;
    // online softmax (branchless)
    const bool upd = sv > m;
    const float mn = upd ? sv : m;
    const float f2 = upd ? __expf(m - sv) : 1.0f;
    const float e = __expf(sv - mn);
    l = l * f2 + e;
    m = mn;
    #pragma unroll
    for (int d4 = 0; d4 < DH / 4; ++d4) {
      const float4 vv = *reinterpret_cast<const float4*>(&vs[j * DH + d4 * 4]);
      acc[d4*4+0] = acc[d4*4+0] * f2 + e * vv.x;
      acc[d4*4+1] = acc[d4*4+1] * f2 + e * vv.y;
      acc[d4*4+2] = acc[d4*4+2] * f2 + e * vv.z;
      acc[d4*4+3] = acc[d4*4+3] * f2 + e * vv.w;
    }
  }
  const float inv = 1.0f / l;
  // av is full-size, b-major: row b*SQ + i
  float* op = av + ((size_t)b * SQ + i) * DM + n * DH;
  #pragma unroll
  for (int d4 = 0; d4 < DH / 4; ++d4) {
    float4 o;
    o.x = acc[d4*4+0] * inv; o.y = acc[d4*4+1] * inv;
    o.z = acc[d4*4+2] * inv; o.w = acc[d4*4+3] * inv;
    reinterpret_cast<float4*>(op)[d4] = o;
  }
}

// ---------------------------------------------------------------------------
extern "C" void kernel_launch(void* const* d_in, const int* in_sizes, int n_in,
                              void* d_out, int out_size, void* d_ws, size_t ws_size,
                              hipStream_t stream) {
  const float* inp   = (const float*)d_in[0];
  const float* ln1_g = (const float*)d_in[1];
  const float* ln1_b = (const float*)d_in[2];
  const float* ln2_g = (const float*)d_in[3];
  const float* ln2_b = (const float*)d_in[4];
  const float* Wqkv  = (const float*)d_in[5];
  const float* Wr    = (const float*)d_in[6];
  const float* Wo    = (const float*)d_in[7];
  const float* rwb   = (const float*)d_in[8];
  const float* rrb   = (const float*)d_in[9];
  float* out = (float*)d_out;
  float* ws  = (float*)d_ws;

  // h' (b-major LN output) lives in d_out; dead before final GEMM writes out.
  float* hprime = out;

  // pick largest batch-chunk CB whose footprint fits ws_size (deterministic).
  const int cands[8] = {192, 96, 48, 24, 12, 6, 4, 2};
  int CB = 2;
  for (int ci = 0; ci < 8; ++ci) {
    const int c = cands[ci];
    const size_t need = ((size_t)c * SQ * (3 * DM)      // qkv chunk
                       + (size_t)BB * SQ * DM           // av (full, b-major)
                       + 2 * (size_t)BB * DM) * 4;      // pe + rhk
    if (need <= ws_size) { CB = c; break; }
  }

  float* qkv_c = ws;
  float* av    = ws + (size_t)CB * SQ * (3 * DM);
  float* pe    = av + (size_t)BB * SQ * DM;
  float* rhk   = pe + (size_t)BB * DM;

  ln2_kernel<<<SQ * BB, 128, 0, stream>>>(inp, ln1_g, ln1_b, ln2_g, ln2_b, hprime);
  posemb_kernel<<<(BB * DM + 255) / 256, 256, 0, stream>>>(inp, pe);
  rhk_kernel<<<dim3(BB, DM / 256), 256, 0, stream>>>(pe, Wr, rhk);

  for (int b0 = 0; b0 < BB; b0 += CB) {
    // QKV GEMM for batch chunk: rows [b0*SQ, (b0+CB)*SQ) of h'
    gemm_nt<<<dim3((3 * DM) / 128, (CB * SQ) / 128), 256, 0, stream>>>(
        hprime + (size_t)b0 * SQ * DM, Wqkv, qkv_c, 3 * DM, DM, 0);
    attn_kernel<<<CB * NH, 192, 0, stream>>>(qkv_c, rhk, rwb, rrb, av, b0);
  }

  // out[s*B+b] = av[b*S+s] · Wo^T  (row-permuted C write)
  gemm_nt<<<dim3(DM / 128, (BB * SQ) / 128), 256, 0, stream>>>(
      av, Wo, out, DM, DM, 1);
}